// Round 10
// baseline (1736.413 us; speedup 1.0000x reference)
//
#include <hip/hip_runtime.h>

// Problem constants
#define NB 8
#define NT 1024
#define ND 768     // = 12*64
#define NH 12
#define NU 64
#define BT (NB*NT)   // 8192
#define SCALE32 ((float)0.03608439182435161)  // fp32(768^-0.5)
#define EPS32 1e-7f

// ---------------------------------------------------------------------------
// numpy baseline-SIMD (SSE2, no FMA) einsum dot over 64 contiguous elements:
// 4 accumulators stride-4, separate mul/add (rounded each), reduce
// (r0+r2)+(r1+r3). __f*_rn blocks hipcc contraction. BITWISE-IDENTICAL.
// ---------------------------------------------------------------------------
__device__ __forceinline__ float dot64_np(const float* a, const float* b)
{
    float r[4];
#pragma unroll
    for (int j = 0; j < 4; j++) r[j] = __fmul_rn(a[j], b[j]);
#pragma unroll
    for (int i = 1; i < 16; i++)
#pragma unroll
        for (int j = 0; j < 4; j++)
            r[j] = __fadd_rn(r[j], __fmul_rn(a[i * 4 + j], b[i * 4 + j]));
    return __fadd_rn(__fadd_rn(r[0], r[2]), __fadd_rn(r[1], r[3]));
}

// ---------------------------------------------------------------------------
// Mask decode with byte/int32 layout sniff (mask is all-ones in practice).
// ---------------------------------------------------------------------------
__global__ __launch_bounds__(256) void mask_k(
    const unsigned char* __restrict__ mb, float* __restrict__ mf)
{
    __shared__ int cntOff, cntAll;
    if (threadIdx.x == 0) { cntOff = 0; cntAll = 0; }
    __syncthreads();
    int lo = 0, la = 0;
    for (int i = threadIdx.x; i < BT; i += 256)
        if (mb[i] != 0) { la++; if ((i & 3) != 0) lo++; }
    atomicAdd(&cntOff, lo);
    atomicAdd(&cntAll, la);
    __syncthreads();
    const bool int32mode = (cntOff == 0) && (cntAll != 0);
    if (int32mode) {
        const int* mi = (const int*)mb;
        for (int i = threadIdx.x; i < BT; i += 256)
            mf[i] = (mi[i] != 0) ? 1.f : 0.f;
    } else {
        for (int i = threadIdx.x; i < BT; i += 256)
            mf[i] = (mb[i] != 0) ? 1.f : 0.f;
    }
}

// ---------------------------------------------------------------------------
// OpenBLAS-mimic sgemm: 128x64 tile, 8x4 micro (R9 champion). kc=384 panel
// split preserved bitwise. grid (64,12). Unchanged.
// ---------------------------------------------------------------------------
__global__ __launch_bounds__(256) void gemmseq(
    const float* __restrict__ A, const float* __restrict__ W,
    const float* __restrict__ R, float* __restrict__ C)
{
    __shared__ float sA[64][132];  // [k][m], transposed, 128 m + 4 pad
    __shared__ float sB[64][68];   // [k][n]

    const int t = threadIdx.x;
    const int mbase = blockIdx.x * 128;
    const int nbase = blockIdx.y * 64;
    const int m0 = (t >> 4) * 8;
    const int n0 = (t & 15) * 4;

    float acc[8][4], accA[8][4];
#pragma unroll
    for (int i = 0; i < 8; i++)
#pragma unroll
        for (int j = 0; j < 4; j++) { acc[i][j] = 0.f; accA[i][j] = 0.f; }

    for (int k0 = 0; k0 < 768; k0 += 64) {
        __syncthreads();
#pragma unroll
        for (int i = 0; i < 8; i++) {           // A tile: 128 rows x 64 k
            const int idx = t + i * 256;        // 0..2047
            const int ar = idx >> 4;            // 0..127
            const int ak4 = (idx & 15) * 4;     // 0..60
            const float4 a4 = *(const float4*)&A[(size_t)(mbase + ar) * 768 + k0 + ak4];
            sA[ak4 + 0][ar] = a4.x;
            sA[ak4 + 1][ar] = a4.y;
            sA[ak4 + 2][ar] = a4.z;
            sA[ak4 + 3][ar] = a4.w;
        }
#pragma unroll
        for (int i = 0; i < 4; i++) {           // B tile: 64 rows x 64 n
            const int idx = t + i * 256;        // 0..1023
            const int br = idx >> 4;            // 0..63
            const int bk4 = (idx & 15) * 4;     // 0..60
            *(float4*)&sB[br][bk4] =
                *(const float4*)&W[(size_t)(k0 + br) * 768 + nbase + bk4];
        }
        __syncthreads();

        for (int kk = 0; kk < 64; kk++) {
            float av[8], bv[4];
            *(float4*)&av[0] = *(const float4*)&sA[kk][m0];
            *(float4*)&av[4] = *(const float4*)&sA[kk][m0 + 4];
            *(float4*)&bv[0] = *(const float4*)&sB[kk][n0];
#pragma unroll
            for (int i = 0; i < 8; i++)
#pragma unroll
                for (int j = 0; j < 4; j++)
                    acc[i][j] = fmaf(av[i], bv[j], acc[i][j]);
        }

        if (k0 + 64 == 384) {   // end of first kc panel (OpenBLAS kc=384)
#pragma unroll
            for (int i = 0; i < 8; i++)
#pragma unroll
                for (int j = 0; j < 4; j++) {
                    accA[i][j] = acc[i][j];
                    acc[i][j] = 0.f;
                }
        }
    }

#pragma unroll
    for (int i = 0; i < 8; i++)
#pragma unroll
        for (int j = 0; j < 4; j++) {
            const size_t idx = (size_t)(mbase + m0 + i) * 768 + nbase + n0 + j;
            float o = __fadd_rn(accA[i][j], acc[i][j]);  // C = panel0 + panel1
            if (R) o = __fadd_rn(o, R[idx]);             // np: out = tmp + x
            C[idx] = o;
        }
}

// ---------------------------------------------------------------------------
// Denominator (champion fallback): one THREAD per row, wave-uniform K loads,
// numpy pairwise trees. grid 768 x 128, XCD-swizzled.
// ---------------------------------------------------------------------------
__global__ __launch_bounds__(128) void denom_np(
    const float* __restrict__ Q, const float* __restrict__ K,
    const float* __restrict__ MF, float* __restrict__ D)
{
    const int bid = blockIdx.x;
    const int lb  = (bid & 7) * 96 + (bid >> 3);
    const int gid = lb * 128 + threadIdx.x;
    const int bh = gid >> 10;
    const int row = gid & 1023;
    const int b = bh / NH, h = bh % NH;
    const int bh_u = __builtin_amdgcn_readfirstlane(bh);
    const int b_u = bh_u / NH, h_u = bh_u % NH;

    const float mq = MF[b * NT + row];

    float qr[64];
    const float4* qp = (const float4*)&Q[((size_t)(b * NT + row)) * ND + h * 64];
#pragma unroll
    for (int i = 0; i < 16; i++) *(float4*)&qr[i * 4] = qp[i];

    const float* Kb = &K[((size_t)(b_u * NT)) * ND + h_u * 64];
    const float* MFb = &MF[b_u * NT];

    float Bi[8];
    for (int c = 0; c < 8; c++) {
        float b8[8];
        for (int s = 0; s < 128; s++) {
            const int sg = c * 128 + s;
            const float dt = dot64_np(qr, Kb + (size_t)sg * ND);
            float sc = __fmul_rn(dt, SCALE32);
            sc = __fmul_rn(sc, MFb[sg]);
            sc = __fmul_rn(sc, mq);
            const int j = s & 7;
            if (s < 8) b8[j] = sc;
            else       b8[j] = __fadd_rn(b8[j], sc);
        }
        Bi[c] = __fadd_rn(__fadd_rn(__fadd_rn(b8[0], b8[1]), __fadd_rn(b8[2], b8[3])),
                          __fadd_rn(__fadd_rn(b8[4], b8[5]), __fadd_rn(b8[6], b8[7])));
    }

    D[(size_t)bh * NT + row] = __fadd_rn(
        __fadd_rn(__fadd_rn(Bi[0], Bi[1]), __fadd_rn(Bi[2], Bi[3])),
        __fadd_rn(__fadd_rn(Bi[4], Bi[5]), __fadd_rn(Bi[6], Bi[7])));
}

// ---------------------------------------------------------------------------
// Denominator + score store: identical arithmetic to denom_np, additionally
// stores sc (post-mask, post-mq — the exact float attn recomputes) to
// S[bh][s][t] (t-contiguous -> lane-coalesced 256B stores per s).
// ---------------------------------------------------------------------------
__global__ __launch_bounds__(128) void denom_s(
    const float* __restrict__ Q, const float* __restrict__ K,
    const float* __restrict__ MF, float* __restrict__ D,
    float* __restrict__ S)
{
    const int bid = blockIdx.x;
    const int lb  = (bid & 7) * 96 + (bid >> 3);
    const int gid = lb * 128 + threadIdx.x;
    const int bh = gid >> 10;
    const int row = gid & 1023;
    const int b = bh / NH, h = bh % NH;
    const int bh_u = __builtin_amdgcn_readfirstlane(bh);
    const int b_u = bh_u / NH, h_u = bh_u % NH;

    const float mq = MF[b * NT + row];

    float qr[64];
    const float4* qp = (const float4*)&Q[((size_t)(b * NT + row)) * ND + h * 64];
#pragma unroll
    for (int i = 0; i < 16; i++) *(float4*)&qr[i * 4] = qp[i];

    const float* Kb = &K[((size_t)(b_u * NT)) * ND + h_u * 64];
    const float* MFb = &MF[b_u * NT];
    float* Sb = S + (size_t)bh * NT * NT + row;   // + s*NT per step

    float Bi[8];
    for (int c = 0; c < 8; c++) {
        float b8[8];
        for (int s = 0; s < 128; s++) {
            const int sg = c * 128 + s;
            const float dt = dot64_np(qr, Kb + (size_t)sg * ND);
            float sc = __fmul_rn(dt, SCALE32);
            sc = __fmul_rn(sc, MFb[sg]);
            sc = __fmul_rn(sc, mq);
            Sb[(size_t)sg * NT] = sc;             // coalesced across lanes
            const int j = s & 7;
            if (s < 8) b8[j] = sc;
            else       b8[j] = __fadd_rn(b8[j], sc);
        }
        Bi[c] = __fadd_rn(__fadd_rn(__fadd_rn(b8[0], b8[1]), __fadd_rn(b8[2], b8[3])),
                          __fadd_rn(__fadd_rn(b8[4], b8[5]), __fadd_rn(b8[6], b8[7])));
    }

    D[(size_t)bh * NT + row] = __fadd_rn(
        __fadd_rn(__fadd_rn(Bi[0], Bi[1]), __fadd_rn(Bi[2], Bi[3])),
        __fadd_rn(__fadd_rn(Bi[4], Bi[5]), __fadd_rn(Bi[6], Bi[7])));
}

// ---------------------------------------------------------------------------
// Attention out (champion fallback): one THREAD per row, recomputes scores.
// grid 768 x 128, XCD-swizzled.
// ---------------------------------------------------------------------------
__global__ __launch_bounds__(128) void attn_np(
    const float* __restrict__ K, const float* __restrict__ V,
    const float* __restrict__ D, const float* __restrict__ MF,
    float* __restrict__ QA)
{
    const int bid = blockIdx.x;
    const int lb  = (bid & 7) * 96 + (bid >> 3);
    const int gid = lb * 128 + threadIdx.x;
    const int bh = gid >> 10;
    const int row = gid & 1023;
    const int b = bh / NH, h = bh % NH;
    const int bh_u = __builtin_amdgcn_readfirstlane(bh);
    const int b_u = bh_u / NH, h_u = bh_u % NH;

    const float mq = MF[b * NT + row];
    const float De = __fadd_rn(D[(size_t)bh * NT + row], EPS32);

    float qr[64];
    const float4* qp = (const float4*)&QA[((size_t)(b * NT + row)) * ND + h * 64];
#pragma unroll
    for (int i = 0; i < 16; i++) *(float4*)&qr[i * 4] = qp[i];

    float o[64];
#pragma unroll
    for (int j = 0; j < 64; j++) o[j] = 0.f;

    const float* Kb = &K[((size_t)(b_u * NT)) * ND + h_u * 64];
    const float* Vb = &V[((size_t)(b_u * NT)) * ND + h_u * 64];
    const float* MFb = &MF[b_u * NT];

    for (int s = 0; s < NT; s++) {
        const float dt = dot64_np(qr, Kb + (size_t)s * ND);
        float sc = __fmul_rn(dt, SCALE32);
        sc = __fmul_rn(sc, MFb[s]);
        sc = __fmul_rn(sc, mq);
        const float p = __fdiv_rn(sc, De);
        const float* vp = Vb + (size_t)s * ND;
#pragma unroll
        for (int j = 0; j < 64; j++)
            o[j] = __fadd_rn(o[j], __fmul_rn(p, vp[j]));
    }

    float4* op = (float4*)&QA[((size_t)(b * NT + row)) * ND + h * 64];
#pragma unroll
    for (int i = 0; i < 16; i++) op[i] = *(float4*)&o[i * 4];
}

// ---------------------------------------------------------------------------
// Attention out, score-reading: no q, no dot — reads the bit-identical sc
// from S[bh][s][t] (coalesced b32 per s), p = fdiv(sc, De) (same bits),
// o[j] chains over s ascending unchanged. Per-iter body ~140 insts vs 260;
// SGPR file only carries the V row now -> the serialization that capped
// R2/R9 at VALUBusy 31% is halved. grid 768 x 128, XCD-swizzled.
// ---------------------------------------------------------------------------
__global__ __launch_bounds__(128) void attn_s(
    const float* __restrict__ S, const float* __restrict__ V,
    const float* __restrict__ D, float* __restrict__ QA)
{
    const int bid = blockIdx.x;
    const int lb  = (bid & 7) * 96 + (bid >> 3);
    const int gid = lb * 128 + threadIdx.x;
    const int bh = gid >> 10;
    const int row = gid & 1023;
    const int b = bh / NH, h = bh % NH;
    const int bh_u = __builtin_amdgcn_readfirstlane(bh);
    const int b_u = bh_u / NH, h_u = bh_u % NH;

    const float De = __fadd_rn(D[(size_t)bh * NT + row], EPS32);

    float o[64];
#pragma unroll
    for (int j = 0; j < 64; j++) o[j] = 0.f;

    const float* Vb = &V[((size_t)(b_u * NT)) * ND + h_u * 64];
    const float* Srow = S + (size_t)bh * NT * NT + row;   // + s*NT per step

    for (int s = 0; s < NT; s++) {
        const float sc = Srow[(size_t)s * NT];            // coalesced
        const float p = __fdiv_rn(sc, De);
        const float* vp = Vb + (size_t)s * ND;            // uniform v
#pragma unroll
        for (int j = 0; j < 64; j++)
            o[j] = __fadd_rn(o[j], __fmul_rn(p, vp[j]));  // np SSE2 axpy
    }

    float4* op = (float4*)&QA[((size_t)(b * NT + row)) * ND + h * 64];
#pragma unroll
    for (int i = 0; i < 16; i++) op[i] = *(float4*)&o[i * 4];
}

// ---------------------------------------------------------------------------
// Row norm, numpy-faithful pairwise mean via ONE WAVE per row (unchanged).
// ---------------------------------------------------------------------------
__global__ __launch_bounds__(256) void rownorm_np(
    float* __restrict__ Y, const float* __restrict__ gamma,
    const float* __restrict__ beta)
{
    const int wave = threadIdx.x >> 6, lane = threadIdx.x & 63;
    const int row = blockIdx.x * 4 + wave;
    float* yr = Y + (size_t)row * ND;
    const int c = lane >> 3, j = lane & 7;

    const float* a = yr + c * 96;
    float r = a[j];
#pragma unroll
    for (int i = 1; i < 12; i++) r = __fadd_rn(r, a[i * 8 + j]);

    r = __fadd_rn(r, __shfl_xor(r, 1, 64));
    r = __fadd_rn(r, __shfl_xor(r, 2, 64));
    r = __fadd_rn(r, __shfl_xor(r, 4, 64));
    r = __fadd_rn(r, __shfl_xor(r, 8, 64));
    r = __fadd_rn(r, __shfl_xor(r, 16, 64));
    r = __fadd_rn(r, __shfl_xor(r, 32, 64));

    const float m = __fdiv_rn(r, 768.0f);
    const float mpe = __fadd_rn(m, EPS32);

#pragma unroll
    for (int i = 0; i < 12; i++) {
        const int idx = i * 64 + lane;
        const float v = yr[idx];
        float o = __fsub_rn(v, m);
        o = __fmul_rn(gamma[idx], o);
        o = __fdiv_rn(o, mpe);
        o = __fadd_rn(o, beta[idx]);
        yr[idx] = o;
    }
}

// ---------------------------------------------------------------------------
extern "C" void kernel_launch(void* const* d_in, const int* in_sizes, int n_in,
                              void* d_out, int out_size, void* d_ws, size_t ws_size,
                              hipStream_t stream)
{
    (void)in_sizes; (void)n_in; (void)out_size;
    const float* x     = (const float*)d_in[0];
    const unsigned char* maskb = (const unsigned char*)d_in[1];
    const float* wq    = (const float*)d_in[2];
    const float* wk    = (const float*)d_in[3];
    const float* wv    = (const float*)d_in[4];
    const float* wf    = (const float*)d_in[5];
    const float* gamma = (const float*)d_in[6];
    const float* beta  = (const float*)d_in[7];

    float* ws = (float*)d_ws;
    float* MF = ws;                             // 8192
    float* D  = MF + BT;                        // 96*1024
    float* Q  = D + (size_t)96 * NT;            // 8192*768 (becomes A)
    float* K  = Q + (size_t)BT * ND;            // 8192*768
    float* V  = K + (size_t)BT * ND;            // 8192*768
    float* S  = V + (size_t)BT * ND;            // 96*1024*1024 (optional)
    float* Y  = (float*)d_out;

    const size_t base_floats = (size_t)BT + (size_t)96 * NT + 3 * (size_t)BT * ND;
    const size_t need_bytes  = (base_floats + (size_t)96 * NT * NT) * sizeof(float);
    const bool use_s = (ws_size >= need_bytes);

    mask_k<<<1, 256, 0, stream>>>(maskb, MF);
    gemmseq<<<dim3(64, 12), 256, 0, stream>>>(x, wq, nullptr, Q);
    gemmseq<<<dim3(64, 12), 256, 0, stream>>>(x, wk, nullptr, K);
    gemmseq<<<dim3(64, 12), 256, 0, stream>>>(x, wv, nullptr, V);
    if (use_s) {
        denom_s<<<768, 128, 0, stream>>>(Q, K, MF, D, S);
        attn_s<<<768, 128, 0, stream>>>(S, V, D, Q);       // Q -> A
    } else {
        denom_np<<<768, 128, 0, stream>>>(Q, K, MF, D);
        attn_np<<<768, 128, 0, stream>>>(K, V, D, MF, Q);  // Q -> A
    }
    gemmseq<<<dim3(64, 12), 256, 0, stream>>>(Q, wf, x, Y);
    rownorm_np<<<2048, 256, 0, stream>>>(Y, gamma, beta);
}